// Round 1
// baseline (396.666 us; speedup 1.0000x reference)
//
#include <hip/hip_runtime.h>
#include <hip/hip_bf16.h>

typedef __attribute__((ext_vector_type(8))) short bf16x8;
typedef __attribute__((ext_vector_type(4))) float f32x4;

// ---------------- shared-memory FWHT (any bit order is valid: H = ⊗H_2) ----
__device__ __forceinline__ void lds_fwht(float* s, int n, int tid, int T) {
  for (int h = 1; h < n; h <<= 1) {
    __syncthreads();
    for (int t = tid; t < (n >> 1); t += T) {
      int i0 = ((t & ~(h - 1)) << 1) | (t & (h - 1));
      int i1 = i0 + h;
      float a = s[i0], b = s[i1];
      s[i0] = a + b;
      s[i1] = a - b;
    }
  }
  __syncthreads();
}

// ---------------- m2_small = FWHT_2048(B[:2048] * theta) for W1 (blk 0) / W2 (blk 1)
__global__ __launch_bounds__(256) void k_m2small(
    const float* __restrict__ theta, const float* __restrict__ BB0,
    const float* __restrict__ BB1, float* __restrict__ out) {
  __shared__ __align__(16) float s[2048];
  const float* BB = blockIdx.x ? BB1 : BB0;
  float* o = out + blockIdx.x * 2048;
  int tid = threadIdx.x;
  for (int i = tid; i < 2048; i += 256) s[i] = BB[i] * theta[i];
  lds_fwht(s, 2048, tid, 256);
  for (int i = tid; i < 2048; i += 256) o[i] = s[i];
}

// ---------------- pass 1: gather(Pi)*GG -> FWHT over bits 0..12 (chunks of 8192)
// also accumulates sum(GG^2) into *sumsq (zeroed beforehand).
__global__ __launch_bounds__(512) void k_f1(
    const int* __restrict__ Pi, const float* __restrict__ GG,
    const float* __restrict__ m2s, float* __restrict__ out,
    float* __restrict__ sumsq) {
  __shared__ __align__(16) float tab[2048];
  __shared__ __align__(16) float s[8192];
  int tid = threadIdx.x;
  for (int i = tid; i < 2048; i += 512) tab[i] = m2s[i];
  __syncthreads();
  long base = (long)blockIdx.x * 8192;
  const int4* p4 = (const int4*)(Pi + base);
  const float4* g4 = (const float4*)(GG + base);
  float lsum = 0.f;
  for (int t = tid; t < 2048; t += 512) {
    int4 p = p4[t];
    float4 g = g4[t];
    lsum += g.x * g.x + g.y * g.y + g.z * g.z + g.w * g.w;
    float4 v;
    v.x = tab[p.x & 2047] * g.x;
    v.y = tab[p.y & 2047] * g.y;
    v.z = tab[p.z & 2047] * g.z;
    v.w = tab[p.w & 2047] * g.w;
    ((float4*)s)[t] = v;
  }
  // wave-reduce then one atomic per wave
  for (int off = 32; off; off >>= 1) lsum += __shfl_down(lsum, off, 64);
  if ((tid & 63) == 0) atomicAdd(sumsq, lsum);
  lds_fwht(s, 8192, tid, 512);
  float4* o4 = (float4*)(out + base);
  for (int t = tid; t < 2048; t += 512) o4[t] = ((float4*)s)[t];
}

// ---------------- pass 2: FWHT over bits 13..21 (512 values, stride 8192) +
// fused epilogue: W = bf16(init + m5*scale) for flat idx < DD (DD = 288*8192).
__global__ __launch_bounds__(512) void k_f2(
    const float* __restrict__ in, const float* __restrict__ initW,
    const float* __restrict__ sumsq, __hip_bfloat16* __restrict__ outW,
    int DD) {
  __shared__ __align__(16) float s[512 * 20];  // pitch 20: banks + 16B-aligned f4
  int tid = threadIdx.x;
  int l0 = blockIdx.x * 16;
  for (int t = tid; t < 2048; t += 512) {
    int c = t >> 2, g4 = (t & 3) << 2;
    float4 v = *(const float4*)(in + (long)c * 8192 + l0 + g4);
    *(float4*)(&s[c * 20 + g4]) = v;
  }
  for (int h = 1; h < 512; h <<= 1) {
    __syncthreads();
    for (int t = tid; t < 256 * 16; t += 512) {
      int g = t & 15, cb = t >> 4;
      int c0 = ((cb & ~(h - 1)) << 1) | (cb & (h - 1));
      int i0 = c0 * 20 + g, i1 = i0 + 20 * h;
      float a = s[i0], b = s[i1];
      s[i0] = a + b;
      s[i1] = a - b;
    }
  }
  __syncthreads();
  float scale = 1.0f / sqrtf(sumsq[0] * (float)DD);
  int cmax = DD >> 13;  // 288
  for (int t = tid; t < cmax * 16; t += 512) {
    int c = t >> 4, g = t & 15;
    long i = (long)c * 8192 + l0 + g;
    float v = initW[i] + s[c * 20 + g] * scale;
    outW[i] = __float2bfloat16(v);
  }
}

// ---------------- whole fastfood pipeline for a bias (single block) ----------
__global__ __launch_bounds__(512) void k_bias(
    const float* __restrict__ theta, const float* __restrict__ BB,
    const int* __restrict__ Pi, const float* __restrict__ GG,
    const float* __restrict__ initb, float* __restrict__ outb,
    int LL, int K, int DD) {
  __shared__ __align__(16) float s[6144];  // tab[K] + m4[LL]
  __shared__ float red[16];
  float* tab = s;
  float* m4 = s + K;
  int tid = threadIdx.x;
  const int T = 512;
  for (int i = tid; i < K; i += T) tab[i] = BB[i] * theta[i];
  lds_fwht(tab, K, tid, T);
  float lsum = 0.f;
  for (int i = tid; i < LL; i += T) {
    float g = GG[i];
    lsum += g * g;
    m4[i] = tab[Pi[i] & (K - 1)] * g;
  }
  for (int off = 32; off; off >>= 1) lsum += __shfl_down(lsum, off, 64);
  if ((tid & 63) == 0) red[tid >> 6] = lsum;
  __syncthreads();
  float S = 0.f;
  for (int w = 0; w < (T >> 6); ++w) S += red[w];
  lds_fwht(m4, LL, tid, T);
  float scale = 1.0f / sqrtf(S * (float)DD);
  for (int i = tid; i < DD; i += T) outb[i] = initb[i] + m4[i] * scale;
}

// ---------------- fp32 -> bf16 convert ----------
__global__ __launch_bounds__(256) void k_convx(const float* __restrict__ x,
                                               __hip_bfloat16* __restrict__ xb,
                                               int n) {
  int i = blockIdx.x * 256 + threadIdx.x;
  if (i < n) xb[i] = __float2bfloat16(x[i]);
}

// ---------------- MFMA GEMM: C[m][n] = act(sum_k A[m][k]*B[n][k] + bias[n]) --
// A: MxK bf16 row-major, B: NxK bf16 row-major. Wave tile: 16(M) x 16*NACC(N).
template <int NACC, bool RELU, bool OUT_BF16>
__global__ __launch_bounds__(256) void k_gemm(
    const __hip_bfloat16* __restrict__ A, const __hip_bfloat16* __restrict__ B,
    const float* __restrict__ bias, void* __restrict__ C, int M, int N, int K) {
  int wid = blockIdx.x * 4 + (threadIdx.x >> 6);
  int lane = threadIdx.x & 63;
  int ntiles = N / (16 * NACC);
  int mt = wid / ntiles, nt = wid % ntiles;
  if (mt * 16 >= M) return;
  int ml = lane & 15;
  int q = lane >> 4;
  const short* As = (const short*)A;
  const short* Bs = (const short*)B;
  long arow = (long)(mt * 16 + ml) * K + q * 8;
  f32x4 acc[NACC] = {};
  for (int k = 0; k < K; k += 32) {
    bf16x8 av = *(const bf16x8*)(As + arow + k);
#pragma unroll
    for (int a = 0; a < NACC; ++a) {
      int n = nt * 16 * NACC + a * 16 + ml;
      bf16x8 bv = *(const bf16x8*)(Bs + (long)n * K + q * 8 + k);
      acc[a] = __builtin_amdgcn_mfma_f32_16x16x32_bf16(av, bv, acc[a], 0, 0, 0);
    }
  }
#pragma unroll
  for (int a = 0; a < NACC; ++a) {
    int n = nt * 16 * NACC + a * 16 + ml;
    float bv = bias[n];
#pragma unroll
    for (int r = 0; r < 4; ++r) {
      int mm = mt * 16 + q * 4 + r;
      float v = acc[a][r] + bv;
      if (RELU) v = fmaxf(v, 0.f);
      if (OUT_BF16)
        ((__hip_bfloat16*)C)[(long)mm * N + n] = __float2bfloat16(v);
      else
        ((float*)C)[(long)mm * N + n] = v;
    }
  }
}

// ---------------- workspace layout (bytes) ----------
#define LLW 4194304
#define DDW 2359296
#define OFF_M2S 0                            // 2*2048 f32
#define OFF_SUM (16 * 1024)                  // 2 f32
#define OFF_M4 (32 * 1024)                   // LLW f32
#define OFF_W1B (OFF_M4 + LLW * 4)           // DDW bf16
#define OFF_W2B (OFF_W1B + DDW * 2)          // DDW bf16
#define OFF_HB (OFF_W2B + DDW * 2)           // 256*3072 bf16
#define OFF_XB (OFF_HB + 786432 * 2)         // 256*768 bf16
#define OFF_B1 (OFF_XB + 196608 * 2)         // 3072 f32
#define OFF_B2 (OFF_B1 + 3072 * 4)           // 768 f32

extern "C" void kernel_launch(void* const* d_in, const int* in_sizes, int n_in,
                              void* d_out, int out_size, void* d_ws,
                              size_t ws_size, hipStream_t stream) {
  const float* x = (const float*)d_in[0];
  const float* theta = (const float*)d_in[1];
  const float* iW1 = (const float*)d_in[2];
  const float* ib1 = (const float*)d_in[3];
  const float* iW2 = (const float*)d_in[4];
  const float* ib2 = (const float*)d_in[5];
  const float* BB_W1 = (const float*)d_in[6];
  const int* Pi_W1 = (const int*)d_in[7];
  const float* GG_W1 = (const float*)d_in[8];
  const float* BB_b1 = (const float*)d_in[9];
  const int* Pi_b1 = (const int*)d_in[10];
  const float* GG_b1 = (const float*)d_in[11];
  const float* BB_W2 = (const float*)d_in[12];
  const int* Pi_W2 = (const int*)d_in[13];
  const float* GG_W2 = (const float*)d_in[14];
  const float* BB_b2 = (const float*)d_in[15];
  const int* Pi_b2 = (const int*)d_in[16];
  const float* GG_b2 = (const float*)d_in[17];

  char* ws = (char*)d_ws;
  float* m2s = (float*)(ws + OFF_M2S);
  float* sumsq = (float*)(ws + OFF_SUM);
  float* m4 = (float*)(ws + OFF_M4);
  __hip_bfloat16* W1b = (__hip_bfloat16*)(ws + OFF_W1B);
  __hip_bfloat16* W2b = (__hip_bfloat16*)(ws + OFF_W2B);
  __hip_bfloat16* hb = (__hip_bfloat16*)(ws + OFF_HB);
  __hip_bfloat16* xb = (__hip_bfloat16*)(ws + OFF_XB);
  float* b1w = (float*)(ws + OFF_B1);
  float* b2w = (float*)(ws + OFF_B2);

  hipMemsetAsync(sumsq, 0, 2 * sizeof(float), stream);

  k_m2small<<<2, 256, 0, stream>>>(theta, BB_W1, BB_W2, m2s);
  k_convx<<<768, 256, 0, stream>>>(x, xb, 196608);
  k_bias<<<1, 512, 0, stream>>>(theta, BB_b1, Pi_b1, GG_b1, ib1, b1w, 4096,
                                2048, 3072);
  k_bias<<<1, 512, 0, stream>>>(theta, BB_b2, Pi_b2, GG_b2, ib2, b2w, 1024,
                                1024, 768);

  // W1 pipeline
  k_f1<<<512, 512, 0, stream>>>(Pi_W1, GG_W1, m2s, m4, sumsq + 0);
  k_f2<<<512, 512, 0, stream>>>(m4, iW1, sumsq + 0, W1b, DDW);
  // W2 pipeline
  k_f1<<<512, 512, 0, stream>>>(Pi_W2, GG_W2, m2s + 2048, m4, sumsq + 1);
  k_f2<<<512, 512, 0, stream>>>(m4, iW2, sumsq + 1, W2b, DDW);

  // h = relu(x @ W1^T + b1)  -> bf16
  k_gemm<4, true, true><<<192, 256, 0, stream>>>(xb, W1b, b1w, hb, 256, 3072,
                                                 768);
  // out = h @ W2^T + b2      -> fp32
  k_gemm<2, false, false><<<96, 256, 0, stream>>>(hb, W2b, b2w, d_out, 256,
                                                  768, 3072);
}

// Round 3
// 328.494 us; speedup vs baseline: 1.2075x; 1.2075x over previous
//
#include <hip/hip_runtime.h>
#include <hip/hip_bf16.h>

typedef __attribute__((ext_vector_type(8))) short bf16x8;
typedef __attribute__((ext_vector_type(4))) float f32x4;

// ---------------- in-register FWHT over N entries spaced S apart ------------
template <int N, int S>
__device__ __forceinline__ void reg_fwht(float* v) {
#pragma unroll
  for (int h = 1; h < N; h <<= 1)
#pragma unroll
    for (int g = 0; g < N; g += 2 * h)
#pragma unroll
      for (int j = 0; j < h; ++j) {
        float a = v[(g + j) * S], b = v[(g + j + h) * S];
        v[(g + j) * S] = a + b;
        v[(g + j + h) * S] = a - b;
      }
}

__device__ __forceinline__ unsigned short f2bf(float f) {
  unsigned u = __float_as_uint(f);
  unsigned r = (u + 0x7fff + ((u >> 16) & 1)) >> 16;
  return (unsigned short)r;
}

// ---------------- generic barriered LDS FWHT (small kernels only) -----------
__device__ __forceinline__ void lds_fwht(float* s, int n, int tid, int T) {
  for (int h = 1; h < n; h <<= 1) {
    __syncthreads();
    for (int t = tid; t < (n >> 1); t += T) {
      int i0 = ((t & ~(h - 1)) << 1) | (t & (h - 1));
      int i1 = i0 + h;
      float a = s[i0], b = s[i1];
      s[i0] = a + b;
      s[i1] = a - b;
    }
  }
  __syncthreads();
}

// ---------------- m2_small = FWHT_2048(B[:2048] * theta) --------------------
__global__ __launch_bounds__(256) void k_m2small(
    const float* __restrict__ theta, const float* __restrict__ BB0,
    const float* __restrict__ BB1, float* __restrict__ out) {
  __shared__ __align__(16) float s[2048];
  const float* BB = blockIdx.x ? BB1 : BB0;
  float* o = out + blockIdx.x * 2048;
  int tid = threadIdx.x;
  for (int i = tid; i < 2048; i += 256) s[i] = BB[i] * theta[i];
  lds_fwht(s, 2048, tid, 256);
  for (int i = tid; i < 2048; i += 256) o[i] = s[i];
}

// ---------------- pass 1: gather(Pi)*GG -> FWHT over bits 0..12 -------------
// Register-based: 256 thr x 32 regs per 8192-chunk; radix 8 (bits 10..12),
// radix 32 (bits 5..9), radix 32 (bits 0..4); 2 LDS exchanges, 3 barriers.
// LDS addr pad: A(i) = i + 4*(i>>5)  (monotone+injective, 16B-aligned,
// <=2-way banks).
__global__ __launch_bounds__(256) void k_f1(
    const int* __restrict__ Pi, const float* __restrict__ GG,
    const float* __restrict__ m2s, float* __restrict__ out,
    float* __restrict__ sumsq) {
  __shared__ __align__(16) float tab[2048];
  __shared__ __align__(16) float s[9216];
  int t = threadIdx.x;
  for (int u = t; u < 512; u += 256)
    ((float4*)tab)[u] = ((const float4*)m2s)[u];
  __syncthreads();

  long base = (long)blockIdx.x * 8192;
  const int4* p4 = (const int4*)(Pi + base);
  const float4* g4 = (const float4*)(GG + base);
  float v[32];
  float lsum = 0.f;
#pragma unroll
  for (int j = 0; j < 8; ++j) {  // element i = t*4 + e + j*1024
    int4 p = p4[t + j * 256];
    float4 g = g4[t + j * 256];
    lsum += g.x * g.x + g.y * g.y + g.z * g.z + g.w * g.w;
    v[j * 4 + 0] = tab[p.x & 2047] * g.x;
    v[j * 4 + 1] = tab[p.y & 2047] * g.y;
    v[j * 4 + 2] = tab[p.z & 2047] * g.z;
    v[j * 4 + 3] = tab[p.w & 2047] * g.w;
  }
  for (int off = 32; off; off >>= 1) lsum += __shfl_down(lsum, off, 64);
  if ((t & 63) == 0) atomicAdd(sumsq, lsum);

  // bits 10..12 (j index), per e
#pragma unroll
  for (int e = 0; e < 4; ++e) reg_fwht<8, 4>(v + e);

#pragma unroll
  for (int j = 0; j < 8; ++j) {
    int A = t * 4 + 4 * (t >> 3) + j * 1152;  // i = t*4 + j*1024
    *(float4*)(s + A) = make_float4(v[j * 4], v[j * 4 + 1], v[j * 4 + 2],
                                    v[j * 4 + 3]);
  }
  __syncthreads();

  // bits 5..9: thread owns bits0..4 = t&31, bits10..12 = t>>5
  float w[32];
  {
    int b = (t & 31) + (t >> 5) * 1024;
#pragma unroll
    for (int j2 = 0; j2 < 32; ++j2) {
      int i = b + j2 * 32;
      w[j2] = s[i + 4 * (i >> 5)];
    }
    reg_fwht<32, 1>(w);
#pragma unroll
    for (int j2 = 0; j2 < 32; ++j2) {
      int i = b + j2 * 32;
      s[i + 4 * (i >> 5)] = w[j2];
    }
  }
  __syncthreads();

  // bits 0..4: thread owns i = t*32 .. t*32+31 (contiguous)
#pragma unroll
  for (int q = 0; q < 8; ++q) {
    float4 r = *(const float4*)(s + t * 36 + q * 4);
    v[q * 4 + 0] = r.x;
    v[q * 4 + 1] = r.y;
    v[q * 4 + 2] = r.z;
    v[q * 4 + 3] = r.w;
  }
  reg_fwht<32, 1>(v);
  float4* o4 = (float4*)(out + base);
#pragma unroll
  for (int q = 0; q < 8; ++q)
    o4[t * 8 + q] =
        make_float4(v[q * 4], v[q * 4 + 1], v[q * 4 + 2], v[q * 4 + 3]);
}

// ---------------- pass 2: FWHT over bits 13..21 + fused epilogue ------------
// Block tile: 16 cols (l0..l0+15) x 512 rows (stride 8192). 256 thr x 32 regs.
// Radix 32 (row bits 0..4), radix 16x2 (row bits 5..8), then epilogue.
// LDS addr: A(r,c) = r*20 + (r>>5)*16 + c  -- MONOTONE pad (round-2 bug was
// ((r>>5)&1)*16 which collides at r=63/64). 16B-aligned, <=2-way banks.
__global__ __launch_bounds__(256) void k_f2(
    const float* __restrict__ in, const float* __restrict__ initW,
    const float* __restrict__ sumsq, __hip_bfloat16* __restrict__ outW,
    int DD) {
  __shared__ __align__(16) float s[10480];
  int t = threadIdx.x;
  int l0 = blockIdx.x * 16;

#pragma unroll
  for (int u = 0; u < 8; ++u) {  // 2048 float4 tiles
    int idx = t + u * 256;
    int r = idx >> 2, c4 = (idx & 3) * 4;
    float4 val = *(const float4*)(in + (long)r * 8192 + l0 + c4);
    *(float4*)(s + r * 20 + (r >> 5) * 16 + c4) = val;
  }
  __syncthreads();

  // row bits 0..4
  {
    int c = t & 15, rg = t >> 4;
    float w[32];
#pragma unroll
    for (int j = 0; j < 32; ++j) {
      int r = rg * 32 + j;
      w[j] = s[r * 20 + (r >> 5) * 16 + c];
    }
    reg_fwht<32, 1>(w);
#pragma unroll
    for (int j = 0; j < 32; ++j) {
      int r = rg * 32 + j;
      s[r * 20 + (r >> 5) * 16 + c] = w[j];
    }
  }
  __syncthreads();

  // row bits 5..8 (two radix-16 groups per thread)
  {
    int c = t & 15;
    float w[32];
#pragma unroll
    for (int k = 0; k < 2; ++k) {
      int b = (t >> 4) * 2 + k;
#pragma unroll
      for (int j4 = 0; j4 < 16; ++j4) {
        int r = b + 32 * j4;
        w[k * 16 + j4] = s[r * 20 + (r >> 5) * 16 + c];
      }
      reg_fwht<16, 1>(w + k * 16);
#pragma unroll
      for (int j4 = 0; j4 < 16; ++j4) {
        int r = b + 32 * j4;
        s[r * 20 + (r >> 5) * 16 + c] = w[k * 16 + j4];
      }
    }
  }
  __syncthreads();

  // epilogue: rows < DD/8192 (=288): W = bf16(init + m5*scale)
  float scale = 1.0f / sqrtf(sumsq[0] * (float)DD);
  int rmax = DD >> 13;
  int nf4 = rmax * 4;  // f4 chunks (4 cols each)
#pragma unroll
  for (int u = 0; u < 5; ++u) {
    int idx = t + u * 256;
    if (idx < nf4) {
      int r = idx >> 2, c4 = (idx & 3) * 4;
      const float* sp = s + r * 20 + (r >> 5) * 16 + c4;
      long gi = (long)r * 8192 + l0 + c4;
      float4 iv = *(const float4*)(initW + gi);
      ushort4 pk;
      pk.x = f2bf(iv.x + sp[0] * scale);
      pk.y = f2bf(iv.y + sp[1] * scale);
      pk.z = f2bf(iv.z + sp[2] * scale);
      pk.w = f2bf(iv.w + sp[3] * scale);
      *(ushort4*)((unsigned short*)outW + gi) = pk;
    }
  }
}

// ---------------- whole fastfood pipeline for a bias (single block) ---------
__global__ __launch_bounds__(512) void k_bias(
    const float* __restrict__ theta, const float* __restrict__ BB,
    const int* __restrict__ Pi, const float* __restrict__ GG,
    const float* __restrict__ initb, float* __restrict__ outb,
    int LL, int K, int DD) {
  __shared__ __align__(16) float s[6144];
  __shared__ float red[16];
  float* tab = s;
  float* m4 = s + K;
  int tid = threadIdx.x;
  const int T = 512;
  for (int i = tid; i < K; i += T) tab[i] = BB[i] * theta[i];
  lds_fwht(tab, K, tid, T);
  float lsum = 0.f;
  for (int i = tid; i < LL; i += T) {
    float g = GG[i];
    lsum += g * g;
    m4[i] = tab[Pi[i] & (K - 1)] * g;
  }
  for (int off = 32; off; off >>= 1) lsum += __shfl_down(lsum, off, 64);
  if ((tid & 63) == 0) red[tid >> 6] = lsum;
  __syncthreads();
  float S = 0.f;
  for (int w = 0; w < (T >> 6); ++w) S += red[w];
  lds_fwht(m4, LL, tid, T);
  float scale = 1.0f / sqrtf(S * (float)DD);
  for (int i = tid; i < DD; i += T) outb[i] = initb[i] + m4[i] * scale;
}

// ---------------- fp32 -> bf16 convert ----------
__global__ __launch_bounds__(256) void k_convx(const float* __restrict__ x,
                                               __hip_bfloat16* __restrict__ xb,
                                               int n) {
  int i = blockIdx.x * 256 + threadIdx.x;
  if (i < n) xb[i] = __float2bfloat16(x[i]);
}

// ---------------- MFMA GEMM: C[m][n] = act(sum_k A[m][k]*B[n][k] + bias[n]) -
template <int NACC, bool RELU, bool OUT_BF16>
__global__ __launch_bounds__(256) void k_gemm(
    const __hip_bfloat16* __restrict__ A, const __hip_bfloat16* __restrict__ B,
    const float* __restrict__ bias, void* __restrict__ C, int M, int N, int K) {
  int wid = blockIdx.x * 4 + (threadIdx.x >> 6);
  int lane = threadIdx.x & 63;
  int ntiles = N / (16 * NACC);
  int mt = wid / ntiles, nt = wid % ntiles;
  if (mt * 16 >= M) return;
  int ml = lane & 15;
  int q = lane >> 4;
  const short* As = (const short*)A;
  const short* Bs = (const short*)B;
  long arow = (long)(mt * 16 + ml) * K + q * 8;
  f32x4 acc[NACC] = {};
  for (int k = 0; k < K; k += 32) {
    bf16x8 av = *(const bf16x8*)(As + arow + k);
#pragma unroll
    for (int a = 0; a < NACC; ++a) {
      int n = nt * 16 * NACC + a * 16 + ml;
      bf16x8 bv = *(const bf16x8*)(Bs + (long)n * K + q * 8 + k);
      acc[a] = __builtin_amdgcn_mfma_f32_16x16x32_bf16(av, bv, acc[a], 0, 0, 0);
    }
  }
#pragma unroll
  for (int a = 0; a < NACC; ++a) {
    int n = nt * 16 * NACC + a * 16 + ml;
    float bv = bias[n];
#pragma unroll
    for (int r = 0; r < 4; ++r) {
      int mm = mt * 16 + q * 4 + r;
      float vv = acc[a][r] + bv;
      if (RELU) vv = fmaxf(vv, 0.f);
      if (OUT_BF16)
        ((__hip_bfloat16*)C)[(long)mm * N + n] = __float2bfloat16(vv);
      else
        ((float*)C)[(long)mm * N + n] = vv;
    }
  }
}

// ---------------- workspace layout (bytes) ----------
#define LLW 4194304
#define DDW 2359296
#define OFF_M2S 0                            // 2*2048 f32
#define OFF_SUM (16 * 1024)                  // 2 f32
#define OFF_M4 (32 * 1024)                   // LLW f32
#define OFF_W1B (OFF_M4 + LLW * 4)           // DDW bf16
#define OFF_W2B (OFF_W1B + DDW * 2)          // DDW bf16
#define OFF_HB (OFF_W2B + DDW * 2)           // 256*3072 bf16
#define OFF_XB (OFF_HB + 786432 * 2)         // 256*768 bf16
#define OFF_B1 (OFF_XB + 196608 * 2)         // 3072 f32
#define OFF_B2 (OFF_B1 + 3072 * 4)           // 768 f32

extern "C" void kernel_launch(void* const* d_in, const int* in_sizes, int n_in,
                              void* d_out, int out_size, void* d_ws,
                              size_t ws_size, hipStream_t stream) {
  const float* x = (const float*)d_in[0];
  const float* theta = (const float*)d_in[1];
  const float* iW1 = (const float*)d_in[2];
  const float* ib1 = (const float*)d_in[3];
  const float* iW2 = (const float*)d_in[4];
  const float* ib2 = (const float*)d_in[5];
  const float* BB_W1 = (const float*)d_in[6];
  const int* Pi_W1 = (const int*)d_in[7];
  const float* GG_W1 = (const float*)d_in[8];
  const float* BB_b1 = (const float*)d_in[9];
  const int* Pi_b1 = (const int*)d_in[10];
  const float* GG_b1 = (const float*)d_in[11];
  const float* BB_W2 = (const float*)d_in[12];
  const int* Pi_W2 = (const int*)d_in[13];
  const float* GG_W2 = (const float*)d_in[14];
  const float* BB_b2 = (const float*)d_in[15];
  const int* Pi_b2 = (const int*)d_in[16];
  const float* GG_b2 = (const float*)d_in[17];

  char* ws = (char*)d_ws;
  float* m2s = (float*)(ws + OFF_M2S);
  float* sumsq = (float*)(ws + OFF_SUM);
  float* m4 = (float*)(ws + OFF_M4);
  __hip_bfloat16* W1b = (__hip_bfloat16*)(ws + OFF_W1B);
  __hip_bfloat16* W2b = (__hip_bfloat16*)(ws + OFF_W2B);
  __hip_bfloat16* hb = (__hip_bfloat16*)(ws + OFF_HB);
  __hip_bfloat16* xb = (__hip_bfloat16*)(ws + OFF_XB);
  float* b1w = (float*)(ws + OFF_B1);
  float* b2w = (float*)(ws + OFF_B2);

  hipMemsetAsync(sumsq, 0, 2 * sizeof(float), stream);

  k_m2small<<<2, 256, 0, stream>>>(theta, BB_W1, BB_W2, m2s);
  k_convx<<<768, 256, 0, stream>>>(x, xb, 196608);
  k_bias<<<1, 512, 0, stream>>>(theta, BB_b1, Pi_b1, GG_b1, ib1, b1w, 4096,
                                2048, 3072);
  k_bias<<<1, 512, 0, stream>>>(theta, BB_b2, Pi_b2, GG_b2, ib2, b2w, 1024,
                                1024, 768);

  // W1 pipeline
  k_f1<<<512, 256, 0, stream>>>(Pi_W1, GG_W1, m2s, m4, sumsq + 0);
  k_f2<<<512, 256, 0, stream>>>(m4, iW1, sumsq + 0, W1b, DDW);
  // W2 pipeline
  k_f1<<<512, 256, 0, stream>>>(Pi_W2, GG_W2, m2s + 2048, m4, sumsq + 1);
  k_f2<<<512, 256, 0, stream>>>(m4, iW2, sumsq + 1, W2b, DDW);

  // h = relu(x @ W1^T + b1)  -> bf16
  k_gemm<4, true, true><<<192, 256, 0, stream>>>(xb, W1b, b1w, hb, 256, 3072,
                                                 768);
  // out = h @ W2^T + b2      -> fp32
  k_gemm<2, false, false><<<96, 256, 0, stream>>>(hb, W2b, b2w, d_out, 256,
                                                  768, 3072);
}

// Round 4
// 271.022 us; speedup vs baseline: 1.4636x; 1.2121x over previous
//
#include <hip/hip_runtime.h>
#include <hip/hip_bf16.h>

typedef __attribute__((ext_vector_type(8))) short bf16x8;
typedef __attribute__((ext_vector_type(8))) unsigned short u16x8;
typedef __attribute__((ext_vector_type(4))) float f32x4;

// ---------------- in-register FWHT over N entries spaced S apart ------------
template <int N, int S>
__device__ __forceinline__ void reg_fwht(float* v) {
#pragma unroll
  for (int h = 1; h < N; h <<= 1)
#pragma unroll
    for (int g = 0; g < N; g += 2 * h)
#pragma unroll
      for (int j = 0; j < h; ++j) {
        float a = v[(g + j) * S], b = v[(g + j + h) * S];
        v[(g + j) * S] = a + b;
        v[(g + j + h) * S] = a - b;
      }
}

__device__ __forceinline__ unsigned short f2bf(float f) {
  unsigned u = __float_as_uint(f);
  unsigned r = (u + 0x7fff + ((u >> 16) & 1)) >> 16;
  return (unsigned short)r;
}

// generic barriered LDS FWHT (tiny bias2 only)
__device__ __forceinline__ void lds_fwht(float* s, int n, int tid, int T) {
  for (int h = 1; h < n; h <<= 1) {
    __syncthreads();
    for (int t = tid; t < (n >> 1); t += T) {
      int i0 = ((t & ~(h - 1)) << 1) | (t & (h - 1));
      int i1 = i0 + h;
      float a = s[i0], b = s[i1];
      s[i0] = a + b;
      s[i1] = a - b;
    }
  }
  __syncthreads();
}

// ---------------- register FWHT-2048 with 256 threads -----------------------
// input: w[j] = element (t + 256j). pad needs >=2304 floats. dst unpadded.
// pad addr A(i) = i + 4*(i>>5): monotone-injective, <=2-way banks.
__device__ __forceinline__ void fwht2048_block(float w[8], float* pad,
                                               float* dst, int t) {
  reg_fwht<8, 1>(w);  // bits 8..10
#pragma unroll
  for (int j = 0; j < 8; ++j) {
    int i = t + 256 * j;
    pad[i + 4 * (i >> 5)] = w[j];
  }
  __syncthreads();
  {  // bits 0..2: 8 contiguous at 8t (never crosses a 32-group)
    int base = 8 * t + 4 * (t >> 2);
    float4 a = *(float4*)(pad + base);
    float4 b = *(float4*)(pad + base + 4);
    float u[8] = {a.x, a.y, a.z, a.w, b.x, b.y, b.z, b.w};
    reg_fwht<8, 1>(u);
    *(float4*)(pad + base) = make_float4(u[0], u[1], u[2], u[3]);
    *(float4*)(pad + base + 4) = make_float4(u[4], u[5], u[6], u[7]);
  }
  __syncthreads();
  {  // bits 3..5: i = (t&7) + 64*(t>>3) + 8j
    int b0 = (t & 7) + 64 * (t >> 3);
    float u[8];
#pragma unroll
    for (int j = 0; j < 8; ++j) {
      int i = b0 + 8 * j;
      u[j] = pad[i + 4 * (i >> 5)];
    }
    reg_fwht<8, 1>(u);
#pragma unroll
    for (int j = 0; j < 8; ++j) {
      int i = b0 + 8 * j;
      pad[i + 4 * (i >> 5)] = u[j];
    }
  }
  __syncthreads();
  // bits 6..7 (radix-4, 2 groups) -> dst unpadded
#pragma unroll
  for (int g = 0; g < 2; ++g) {
    int b0 = (t & 63) + 256 * ((g << 2) | (t >> 6));
    float u[4];
#pragma unroll
    for (int j = 0; j < 4; ++j) {
      int i = b0 + 64 * j;
      u[j] = pad[i + 4 * (i >> 5)];
    }
    reg_fwht<4, 1>(u);
#pragma unroll
    for (int j = 0; j < 4; ++j) dst[b0 + 64 * j] = u[j];
  }
  __syncthreads();
}

// ---------------- k_pre: m2 tables (blocks 0,1) + x->bf16 (blocks 2..97) ----
__global__ __launch_bounds__(256) void k_pre(
    const float* __restrict__ theta, const float* __restrict__ BB0,
    const float* __restrict__ BB1, float* __restrict__ m2s,
    const float* __restrict__ x, __hip_bfloat16* __restrict__ xb) {
  __shared__ __align__(16) float pad[2304];
  int b = blockIdx.x, t = threadIdx.x;
  if (b < 2) {
    const float* BB = b ? BB1 : BB0;
    float w[8];
#pragma unroll
    for (int j = 0; j < 8; ++j) {
      int i = t + 256 * j;
      w[j] = BB[i] * theta[i];
    }
    fwht2048_block(w, pad, m2s + b * 2048, t);
  } else {
    int id0 = (b - 2) * 256 + t;
#pragma unroll
    for (int it = 0; it < 2; ++it) {
      int id = id0 + it * 24576;
      float4 xv = ((const float4*)x)[id];
      ushort4 o;
      o.x = f2bf(xv.x);
      o.y = f2bf(xv.y);
      o.z = f2bf(xv.z);
      o.w = f2bf(xv.w);
      ((ushort4*)xb)[id] = o;
    }
  }
}

#define LLW 4194304

// ---------------- k_front: f1 x2 pipes (blocks 0..1023) + biases ------------
__global__ __launch_bounds__(256) void k_front(
    const int* __restrict__ Pi1, const float* __restrict__ GG1,
    const int* __restrict__ Pi2, const float* __restrict__ GG2,
    const float* __restrict__ m2s, unsigned short* __restrict__ m4b,
    float* __restrict__ sumsq, const float* __restrict__ theta,
    const float* __restrict__ BBb1, const int* __restrict__ Pib1,
    const float* __restrict__ GGb1, const float* __restrict__ ib1,
    float* __restrict__ b1w, const float* __restrict__ BBb2,
    const int* __restrict__ Pib2, const float* __restrict__ GGb2,
    const float* __restrict__ ib2, float* __restrict__ b2w) {
  __shared__ __align__(16) float tab[2048];
  __shared__ __align__(16) float s[9216];
  int b = blockIdx.x, t = threadIdx.x;

  if (b < 1024) {
    // ---- f1: gather + FWHT-8192 over low 13 bits, bf16 out ----
    int pipe = b >> 9, chunk = b & 511;
    const int* Pi = pipe ? Pi2 : Pi1;
    const float* GG = pipe ? GG2 : GG1;
    const float* mm = m2s + pipe * 2048;
    for (int u = t; u < 512; u += 256) ((float4*)tab)[u] = ((const float4*)mm)[u];
    __syncthreads();

    long base = (long)chunk * 8192;
    const int4* p4 = (const int4*)(Pi + base);
    const float4* g4 = (const float4*)(GG + base);
    float v[32];
    float lsum = 0.f;
#pragma unroll
    for (int j = 0; j < 8; ++j) {  // i = t*4 + e + j*1024
      int4 p = p4[t + j * 256];
      float4 g = g4[t + j * 256];
      lsum += g.x * g.x + g.y * g.y + g.z * g.z + g.w * g.w;
      v[j * 4 + 0] = tab[p.x & 2047] * g.x;
      v[j * 4 + 1] = tab[p.y & 2047] * g.y;
      v[j * 4 + 2] = tab[p.z & 2047] * g.z;
      v[j * 4 + 3] = tab[p.w & 2047] * g.w;
    }
    for (int off = 32; off; off >>= 1) lsum += __shfl_down(lsum, off, 64);
    if ((t & 63) == 0) atomicAdd(sumsq + pipe, lsum);

#pragma unroll
    for (int e = 0; e < 4; ++e) reg_fwht<8, 4>(v + e);  // bits 10..12

#pragma unroll
    for (int j = 0; j < 8; ++j) {
      int A = t * 4 + 4 * (t >> 3) + j * 1152;
      *(float4*)(s + A) =
          make_float4(v[j * 4], v[j * 4 + 1], v[j * 4 + 2], v[j * 4 + 3]);
    }
    __syncthreads();
    {  // bits 5..9
      int b0 = (t & 31) + (t >> 5) * 1024;
      float w[32];
#pragma unroll
      for (int j2 = 0; j2 < 32; ++j2) {
        int i = b0 + j2 * 32;
        w[j2] = s[i + 4 * (i >> 5)];
      }
      reg_fwht<32, 1>(w);
#pragma unroll
      for (int j2 = 0; j2 < 32; ++j2) {
        int i = b0 + j2 * 32;
        s[i + 4 * (i >> 5)] = w[j2];
      }
    }
    __syncthreads();
    // bits 0..4: contiguous 32 per thread
#pragma unroll
    for (int q = 0; q < 8; ++q) {
      float4 r = *(const float4*)(s + t * 36 + q * 4);
      v[q * 4 + 0] = r.x;
      v[q * 4 + 1] = r.y;
      v[q * 4 + 2] = r.z;
      v[q * 4 + 3] = r.w;
    }
    reg_fwht<32, 1>(v);
    unsigned short* o = m4b + (long)pipe * LLW + base + t * 32;
#pragma unroll
    for (int q = 0; q < 4; ++q) {
      u16x8 pk;
#pragma unroll
      for (int e = 0; e < 8; ++e) pk[e] = f2bf(v[q * 8 + e]);
      *(u16x8*)(o + q * 8) = pk;
    }
  } else if (b == 1024) {
    // ---- bias1: LL=4096, K=2048, DD=3072 ----
    float w[8];
#pragma unroll
    for (int j = 0; j < 8; ++j) {
      int i = t + 256 * j;
      w[j] = BBb1[i] * theta[i];
    }
    fwht2048_block(w, s, tab, t);

    float w16[16];
    float lsum = 0.f;
#pragma unroll
    for (int j = 0; j < 16; ++j) {  // i = t + 256j
      int i = t + 256 * j;
      float g = GGb1[i];
      lsum += g * g;
      w16[j] = tab[Pib1[i] & 2047] * g;
    }
    reg_fwht<16, 1>(w16);  // bits 8..11
#pragma unroll
    for (int j = 0; j < 16; ++j) {
      int i = t + 256 * j;
      s[i + 4 * (i >> 5)] = w16[j];
    }
    for (int off = 32; off; off >>= 1) lsum += __shfl_down(lsum, off, 64);
    if ((t & 63) == 0) s[4608 + (t >> 6)] = lsum;
    __syncthreads();
    float S = s[4608] + s[4609] + s[4610] + s[4611];
    {  // bits 0..3: 16 contiguous
      int base16 = 16 * t + 4 * (t >> 1);
      float u[16];
#pragma unroll
      for (int q = 0; q < 4; ++q) {
        float4 r = *(float4*)(s + base16 + q * 4);
        u[q * 4 + 0] = r.x;
        u[q * 4 + 1] = r.y;
        u[q * 4 + 2] = r.z;
        u[q * 4 + 3] = r.w;
      }
      reg_fwht<16, 1>(u);
#pragma unroll
      for (int q = 0; q < 4; ++q)
        *(float4*)(s + base16 + q * 4) =
            make_float4(u[q * 4], u[q * 4 + 1], u[q * 4 + 2], u[q * 4 + 3]);
    }
    __syncthreads();
    {  // bits 4..7 + epilogue
      float scale = 1.0f / sqrtf(S * 3072.0f);
      int b0 = (t & 15) + 256 * (t >> 4);
      float u[16];
#pragma unroll
      for (int j = 0; j < 16; ++j) {
        int i = b0 + 16 * j;
        u[j] = s[i + 4 * (i >> 5)];
      }
      reg_fwht<16, 1>(u);
#pragma unroll
      for (int j = 0; j < 16; ++j) {
        int i = b0 + 16 * j;
        if (i < 3072) b1w[i] = ib1[i] + u[j] * scale;
      }
    }
  } else {
    // ---- bias2: LL=1024, K=1024, DD=768 (generic path, tiny) ----
    float* tab2 = s;
    float* m42 = s + 1024;
    for (int i = t; i < 1024; i += 256) tab2[i] = BBb2[i] * theta[i];
    lds_fwht(tab2, 1024, t, 256);
    float lsum = 0.f;
    for (int i = t; i < 1024; i += 256) {
      float g = GGb2[i];
      lsum += g * g;
      m42[i] = tab2[Pib2[i] & 1023] * g;
    }
    for (int off = 32; off; off >>= 1) lsum += __shfl_down(lsum, off, 64);
    if ((t & 63) == 0) s[2048 + (t >> 6)] = lsum;
    lds_fwht(m42, 1024, t, 256);  // leading barrier covers s[2048..]
    float S = s[2048] + s[2049] + s[2050] + s[2051];
    float scale = 1.0f / sqrtf(S * 768.0f);
    for (int i = t; i < 768; i += 256) b2w[i] = ib2[i] + m42[i] * scale;
  }
}

// ---------------- k_f2c: FWHT over bits 13..21 + epilogue, both pipes -------
__global__ __launch_bounds__(256) void k_f2c(
    const unsigned short* __restrict__ m4b, const float* __restrict__ iW1,
    const float* __restrict__ iW2, const float* __restrict__ sumsq,
    __hip_bfloat16* __restrict__ W1b, __hip_bfloat16* __restrict__ W2b) {
  __shared__ __align__(16) float s[10480];
  int b = blockIdx.x, t = threadIdx.x;
  int pipe = b >> 9;
  int l0 = (b & 511) * 16;
  const unsigned short* mp = m4b + (long)pipe * LLW;
  const float* initW = pipe ? iW2 : iW1;
  unsigned short* outW = (unsigned short*)(pipe ? W2b : W1b);

#pragma unroll
  for (int u = 0; u < 4; ++u) {  // 1024 half-rows of 8 bf16
    int idx = t + u * 256;
    int r = idx >> 1, h8 = (idx & 1) * 8;
    u16x8 raw = *(const u16x8*)(mp + (long)r * 8192 + l0 + h8);
    float* dp = s + r * 20 + (r >> 5) * 16 + h8;
    float4 f0, f1v;
    f0.x = __uint_as_float((unsigned)raw[0] << 16);
    f0.y = __uint_as_float((unsigned)raw[1] << 16);
    f0.z = __uint_as_float((unsigned)raw[2] << 16);
    f0.w = __uint_as_float((unsigned)raw[3] << 16);
    f1v.x = __uint_as_float((unsigned)raw[4] << 16);
    f1v.y = __uint_as_float((unsigned)raw[5] << 16);
    f1v.z = __uint_as_float((unsigned)raw[6] << 16);
    f1v.w = __uint_as_float((unsigned)raw[7] << 16);
    *(float4*)dp = f0;
    *(float4*)(dp + 4) = f1v;
  }
  __syncthreads();

  {  // row bits 0..4
    int c = t & 15, rg = t >> 4;
    float w[32];
#pragma unroll
    for (int j = 0; j < 32; ++j) {
      int r = rg * 32 + j;
      w[j] = s[r * 20 + (r >> 5) * 16 + c];
    }
    reg_fwht<32, 1>(w);
#pragma unroll
    for (int j = 0; j < 32; ++j) {
      int r = rg * 32 + j;
      s[r * 20 + (r >> 5) * 16 + c] = w[j];
    }
  }
  __syncthreads();

  {  // row bits 5..8
    int c = t & 15;
    float w[32];
#pragma unroll
    for (int k = 0; k < 2; ++k) {
      int b0 = (t >> 4) * 2 + k;
#pragma unroll
      for (int j4 = 0; j4 < 16; ++j4) {
        int r = b0 + 32 * j4;
        w[k * 16 + j4] = s[r * 20 + (r >> 5) * 16 + c];
      }
      reg_fwht<16, 1>(w + k * 16);
#pragma unroll
      for (int j4 = 0; j4 < 16; ++j4) {
        int r = b0 + 32 * j4;
        s[r * 20 + (r >> 5) * 16 + c] = w[k * 16 + j4];
      }
    }
  }
  __syncthreads();

  float scale = 1.0f / sqrtf(sumsq[pipe] * 2359296.0f);
#pragma unroll
  for (int u = 0; u < 5; ++u) {  // 288 rows * 4 f4-chunks = 1152
    int idx = t + u * 256;
    if (idx < 1152) {
      int r = idx >> 2, c4 = (idx & 3) * 4;
      const float* sp = s + r * 20 + (r >> 5) * 16 + c4;
      long gi = (long)r * 8192 + l0 + c4;
      float4 iv = *(const float4*)(initW + gi);
      ushort4 pk;
      pk.x = f2bf(iv.x + sp[0] * scale);
      pk.y = f2bf(iv.y + sp[1] * scale);
      pk.z = f2bf(iv.z + sp[2] * scale);
      pk.w = f2bf(iv.w + sp[3] * scale);
      *(ushort4*)(outW + gi) = pk;
    }
  }
}

// ---------------- MFMA GEMM, KCH interleaved K-chains -----------------------
template <int NACC, int KCH, bool RELU, bool OUT_BF16>
__global__ __launch_bounds__(256) void k_gemm(
    const __hip_bfloat16* __restrict__ A, const __hip_bfloat16* __restrict__ B,
    const float* __restrict__ bias, void* __restrict__ C, int M, int N, int K) {
  int wid = blockIdx.x * 4 + (threadIdx.x >> 6);
  int lane = threadIdx.x & 63;
  int ntiles = N / (16 * NACC);
  int mt = wid / ntiles, nt = wid % ntiles;
  if (mt * 16 >= M) return;
  int ml = lane & 15;
  int q = lane >> 4;
  const short* As = (const short*)A;
  const short* Bs = (const short*)B;
  long arow = (long)(mt * 16 + ml) * K + q * 8;
  int KH = K / KCH;
  f32x4 acc[KCH][NACC] = {};
  for (int k = 0; k < KH; k += 32) {
#pragma unroll
    for (int c = 0; c < KCH; ++c) {
      bf16x8 av = *(const bf16x8*)(As + arow + k + c * KH);
#pragma unroll
      for (int a = 0; a < NACC; ++a) {
        int n = nt * 16 * NACC + a * 16 + ml;
        bf16x8 bv = *(const bf16x8*)(Bs + (long)n * K + q * 8 + k + c * KH);
        acc[c][a] =
            __builtin_amdgcn_mfma_f32_16x16x32_bf16(av, bv, acc[c][a], 0, 0, 0);
      }
    }
  }
#pragma unroll
  for (int a = 0; a < NACC; ++a) {
    int n = nt * 16 * NACC + a * 16 + ml;
    float bv = bias[n];
#pragma unroll
    for (int r = 0; r < 4; ++r) {
      float vv = bv;
#pragma unroll
      for (int c = 0; c < KCH; ++c) vv += acc[c][a][r];
      int mm = mt * 16 + q * 4 + r;
      if (RELU) vv = fmaxf(vv, 0.f);
      if (OUT_BF16)
        ((__hip_bfloat16*)C)[(long)mm * N + n] = __float2bfloat16(vv);
      else
        ((float*)C)[(long)mm * N + n] = vv;
    }
  }
}

// ---------------- workspace layout (bytes) ----------------------------------
#define OFF_SUM 0
#define OFF_M2S 256
#define OFF_M4B (OFF_M2S + 16384)          // 2*LLW bf16 = 16 MiB
#define OFF_W1B (OFF_M4B + 2 * LLW * 2)    // 2359296 bf16
#define OFF_W2B (OFF_W1B + 4718592)
#define OFF_HB (OFF_W2B + 4718592)         // 256*3072 bf16
#define OFF_XB (OFF_HB + 1572864)          // 256*768 bf16
#define OFF_B1 (OFF_XB + 393216)           // 3072 f32
#define OFF_B2 (OFF_B1 + 12288)            // 768 f32

extern "C" void kernel_launch(void* const* d_in, const int* in_sizes, int n_in,
                              void* d_out, int out_size, void* d_ws,
                              size_t ws_size, hipStream_t stream) {
  const float* x = (const float*)d_in[0];
  const float* theta = (const float*)d_in[1];
  const float* iW1 = (const float*)d_in[2];
  const float* ib1 = (const float*)d_in[3];
  const float* iW2 = (const float*)d_in[4];
  const float* ib2 = (const float*)d_in[5];
  const float* BB_W1 = (const float*)d_in[6];
  const int* Pi_W1 = (const int*)d_in[7];
  const float* GG_W1 = (const float*)d_in[8];
  const float* BB_b1 = (const float*)d_in[9];
  const int* Pi_b1 = (const int*)d_in[10];
  const float* GG_b1 = (const float*)d_in[11];
  const float* BB_W2 = (const float*)d_in[12];
  const int* Pi_W2 = (const int*)d_in[13];
  const float* GG_W2 = (const float*)d_in[14];
  const float* BB_b2 = (const float*)d_in[15];
  const int* Pi_b2 = (const int*)d_in[16];
  const float* GG_b2 = (const float*)d_in[17];

  char* ws = (char*)d_ws;
  float* sumsq = (float*)(ws + OFF_SUM);
  float* m2s = (float*)(ws + OFF_M2S);
  unsigned short* m4b = (unsigned short*)(ws + OFF_M4B);
  __hip_bfloat16* W1b = (__hip_bfloat16*)(ws + OFF_W1B);
  __hip_bfloat16* W2b = (__hip_bfloat16*)(ws + OFF_W2B);
  __hip_bfloat16* hb = (__hip_bfloat16*)(ws + OFF_HB);
  __hip_bfloat16* xb = (__hip_bfloat16*)(ws + OFF_XB);
  float* b1w = (float*)(ws + OFF_B1);
  float* b2w = (float*)(ws + OFF_B2);

  hipMemsetAsync(sumsq, 0, 8, stream);
  k_pre<<<98, 256, 0, stream>>>(theta, BB_W1, BB_W2, m2s, x, xb);
  k_front<<<1026, 256, 0, stream>>>(Pi_W1, GG_W1, Pi_W2, GG_W2, m2s, m4b,
                                    sumsq, theta, BB_b1, Pi_b1, GG_b1, ib1,
                                    b1w, BB_b2, Pi_b2, GG_b2, ib2, b2w);
  k_f2c<<<1024, 256, 0, stream>>>(m4b, iW1, iW2, sumsq, W1b, W2b);
  k_gemm<2, 1, true, true><<<384, 256, 0, stream>>>(xb, W1b, b1w, hb, 256,
                                                    3072, 768);
  k_gemm<1, 2, false, false><<<192, 256, 0, stream>>>(hb, W2b, b2w, d_out, 256,
                                                      768, 3072);
}

// Round 5
// 226.934 us; speedup vs baseline: 1.7479x; 1.1943x over previous
//
#include <hip/hip_runtime.h>
#include <hip/hip_bf16.h>

typedef __attribute__((ext_vector_type(8))) short bf16x8;
typedef __attribute__((ext_vector_type(8))) unsigned short u16x8;
typedef __attribute__((ext_vector_type(4))) float f32x4;

// ---------------- in-register FWHT over N entries spaced S apart ------------
template <int N, int S>
__device__ __forceinline__ void reg_fwht(float* v) {
#pragma unroll
  for (int h = 1; h < N; h <<= 1)
#pragma unroll
    for (int g = 0; g < N; g += 2 * h)
#pragma unroll
      for (int j = 0; j < h; ++j) {
        float a = v[(g + j) * S], b = v[(g + j + h) * S];
        v[(g + j) * S] = a + b;
        v[(g + j + h) * S] = a - b;
      }
}

__device__ __forceinline__ unsigned short f2bf(float f) {
  unsigned u = __float_as_uint(f);
  unsigned r = (u + 0x7fff + ((u >> 16) & 1)) >> 16;
  return (unsigned short)r;
}

// generic barriered LDS FWHT (tiny bias2 only)
__device__ __forceinline__ void lds_fwht(float* s, int n, int tid, int T) {
  for (int h = 1; h < n; h <<= 1) {
    __syncthreads();
    for (int t = tid; t < (n >> 1); t += T) {
      int i0 = ((t & ~(h - 1)) << 1) | (t & (h - 1));
      int i1 = i0 + h;
      float a = s[i0], b = s[i1];
      s[i0] = a + b;
      s[i1] = a - b;
    }
  }
  __syncthreads();
}

// ---------------- register FWHT-2048 with 256 threads -----------------------
// input: w[j] = element (t + 256j). pad needs >=2304 floats. dst unpadded.
// pad addr A(i) = i + 4*(i>>5): monotone-injective, <=2-way banks.
__device__ __forceinline__ void fwht2048_block(float w[8], float* pad,
                                               float* dst, int t) {
  reg_fwht<8, 1>(w);  // bits 8..10
#pragma unroll
  for (int j = 0; j < 8; ++j) {
    int i = t + 256 * j;
    pad[i + 4 * (i >> 5)] = w[j];
  }
  __syncthreads();
  {  // bits 0..2: 8 contiguous at 8t (never crosses a 32-group)
    int base = 8 * t + 4 * (t >> 2);
    float4 a = *(float4*)(pad + base);
    float4 b = *(float4*)(pad + base + 4);
    float u[8] = {a.x, a.y, a.z, a.w, b.x, b.y, b.z, b.w};
    reg_fwht<8, 1>(u);
    *(float4*)(pad + base) = make_float4(u[0], u[1], u[2], u[3]);
    *(float4*)(pad + base + 4) = make_float4(u[4], u[5], u[6], u[7]);
  }
  __syncthreads();
  {  // bits 3..5: i = (t&7) + 64*(t>>3) + 8j
    int b0 = (t & 7) + 64 * (t >> 3);
    float u[8];
#pragma unroll
    for (int j = 0; j < 8; ++j) {
      int i = b0 + 8 * j;
      u[j] = pad[i + 4 * (i >> 5)];
    }
    reg_fwht<8, 1>(u);
#pragma unroll
    for (int j = 0; j < 8; ++j) {
      int i = b0 + 8 * j;
      pad[i + 4 * (i >> 5)] = u[j];
    }
  }
  __syncthreads();
  // bits 6..7 (radix-4, 2 groups) -> dst unpadded
#pragma unroll
  for (int g = 0; g < 2; ++g) {
    int b0 = (t & 63) + 256 * ((g << 2) | (t >> 6));
    float u[4];
#pragma unroll
    for (int j = 0; j < 4; ++j) {
      int i = b0 + 64 * j;
      u[j] = pad[i + 4 * (i >> 5)];
    }
    reg_fwht<4, 1>(u);
#pragma unroll
    for (int j = 0; j < 4; ++j) dst[b0 + 64 * j] = u[j];
  }
  __syncthreads();
}

// ---------------- k_pre: m2 tables (blocks 0,1) + x->bf16 (blocks 2..97) ----
__global__ __launch_bounds__(256) void k_pre(
    const float* __restrict__ theta, const float* __restrict__ BB0,
    const float* __restrict__ BB1, float* __restrict__ m2s,
    const float* __restrict__ x, __hip_bfloat16* __restrict__ xb) {
  __shared__ __align__(16) float pad[2304];
  int b = blockIdx.x, t = threadIdx.x;
  if (b < 2) {
    const float* BB = b ? BB1 : BB0;
    float w[8];
#pragma unroll
    for (int j = 0; j < 8; ++j) {
      int i = t + 256 * j;
      w[j] = BB[i] * theta[i];
    }
    fwht2048_block(w, pad, m2s + b * 2048, t);
  } else {
    int id0 = (b - 2) * 256 + t;
#pragma unroll
    for (int it = 0; it < 2; ++it) {
      int id = id0 + it * 24576;
      float4 xv = ((const float4*)x)[id];
      ushort4 o;
      o.x = f2bf(xv.x);
      o.y = f2bf(xv.y);
      o.z = f2bf(xv.z);
      o.w = f2bf(xv.w);
      ((ushort4*)xb)[id] = o;
    }
  }
}

#define LLW 4194304

// ---------------- k_front: biases (blocks 0,1) + f1 x2 pipes (2..1025) ------
// NO device atomics: per-block sum(GG^2) partials go to distinct slots.
__global__ __launch_bounds__(256) void k_front(
    const int* __restrict__ Pi1, const float* __restrict__ GG1,
    const int* __restrict__ Pi2, const float* __restrict__ GG2,
    const float* __restrict__ m2s, unsigned short* __restrict__ m4b,
    float* __restrict__ partial, const float* __restrict__ theta,
    const float* __restrict__ BBb1, const int* __restrict__ Pib1,
    const float* __restrict__ GGb1, const float* __restrict__ ib1,
    float* __restrict__ b1w, const float* __restrict__ BBb2,
    const int* __restrict__ Pib2, const float* __restrict__ GGb2,
    const float* __restrict__ ib2, float* __restrict__ b2w) {
  __shared__ __align__(16) float s[9216];  // tab aliases s[0:2048]
  __shared__ float red[4];
  int b = blockIdx.x, t = threadIdx.x;

  if (b >= 2) {
    // ---- f1: gather + FWHT-8192 over low 13 bits, bf16 out ----
    int bb = b - 2;
    int pipe = bb >> 9, chunk = bb & 511;
    const int* Pi = pipe ? Pi2 : Pi1;
    const float* GG = pipe ? GG2 : GG1;
    const float* mm = m2s + pipe * 2048;
    for (int u = t; u < 512; u += 256) ((float4*)s)[u] = ((const float4*)mm)[u];
    __syncthreads();

    long base = (long)chunk * 8192;
    const int4* p4 = (const int4*)(Pi + base);
    const float4* g4 = (const float4*)(GG + base);
    float v[32];
    float lsum = 0.f;
#pragma unroll
    for (int j = 0; j < 8; ++j) {  // i = t*4 + e + j*1024
      int4 p = p4[t + j * 256];
      float4 g = g4[t + j * 256];
      lsum += g.x * g.x + g.y * g.y + g.z * g.z + g.w * g.w;
      v[j * 4 + 0] = s[p.x & 2047] * g.x;
      v[j * 4 + 1] = s[p.y & 2047] * g.y;
      v[j * 4 + 2] = s[p.z & 2047] * g.z;
      v[j * 4 + 3] = s[p.w & 2047] * g.w;
    }
    for (int off = 32; off; off >>= 1) lsum += __shfl_down(lsum, off, 64);
    if ((t & 63) == 0) red[t >> 6] = lsum;

#pragma unroll
    for (int e = 0; e < 4; ++e) reg_fwht<8, 4>(v + e);  // bits 10..12

    __syncthreads();  // tab reads + red writes complete; s reusable
    if (t == 0) partial[pipe * 512 + chunk] = red[0] + red[1] + red[2] + red[3];

#pragma unroll
    for (int j = 0; j < 8; ++j) {
      int A = t * 4 + 4 * (t >> 3) + j * 1152;
      *(float4*)(s + A) =
          make_float4(v[j * 4], v[j * 4 + 1], v[j * 4 + 2], v[j * 4 + 3]);
    }
    __syncthreads();
    {  // bits 5..9
      int b0 = (t & 31) + (t >> 5) * 1024;
      float w[32];
#pragma unroll
      for (int j2 = 0; j2 < 32; ++j2) {
        int i = b0 + j2 * 32;
        w[j2] = s[i + 4 * (i >> 5)];
      }
      reg_fwht<32, 1>(w);
#pragma unroll
      for (int j2 = 0; j2 < 32; ++j2) {
        int i = b0 + j2 * 32;
        s[i + 4 * (i >> 5)] = w[j2];
      }
    }
    __syncthreads();
    // bits 0..4: contiguous 32 per thread
#pragma unroll
    for (int q = 0; q < 8; ++q) {
      float4 r = *(const float4*)(s + t * 36 + q * 4);
      v[q * 4 + 0] = r.x;
      v[q * 4 + 1] = r.y;
      v[q * 4 + 2] = r.z;
      v[q * 4 + 3] = r.w;
    }
    reg_fwht<32, 1>(v);
    unsigned short* o = m4b + (long)pipe * LLW + base + t * 32;
#pragma unroll
    for (int q = 0; q < 4; ++q) {
      u16x8 pk;
#pragma unroll
      for (int e = 0; e < 8; ++e) pk[e] = f2bf(v[q * 8 + e]);
      *(u16x8*)(o + q * 8) = pk;
    }
  } else if (b == 0) {
    // ---- bias1: LL=4096, K=2048, DD=3072 ----
    float* tabd = s + 6144;  // dst region, disjoint from pad/stage regions
    float w[8];
#pragma unroll
    for (int j = 0; j < 8; ++j) {
      int i = t + 256 * j;
      w[j] = BBb1[i] * theta[i];
    }
    fwht2048_block(w, s, tabd, t);

    float w16[16];
    float lsum = 0.f;
#pragma unroll
    for (int j = 0; j < 16; ++j) {  // i = t + 256j
      int i = t + 256 * j;
      float g = GGb1[i];
      lsum += g * g;
      w16[j] = tabd[Pib1[i] & 2047] * g;
    }
    reg_fwht<16, 1>(w16);  // bits 8..11
#pragma unroll
    for (int j = 0; j < 16; ++j) {
      int i = t + 256 * j;
      s[i + 4 * (i >> 5)] = w16[j];  // max addr 4603 < 6144
    }
    for (int off = 32; off; off >>= 1) lsum += __shfl_down(lsum, off, 64);
    if ((t & 63) == 0) s[4608 + (t >> 6)] = lsum;
    __syncthreads();
    float S = s[4608] + s[4609] + s[4610] + s[4611];
    {  // bits 0..3: 16 contiguous
      int base16 = 16 * t + 4 * (t >> 1);
      float u[16];
#pragma unroll
      for (int q = 0; q < 4; ++q) {
        float4 r = *(float4*)(s + base16 + q * 4);
        u[q * 4 + 0] = r.x;
        u[q * 4 + 1] = r.y;
        u[q * 4 + 2] = r.z;
        u[q * 4 + 3] = r.w;
      }
      reg_fwht<16, 1>(u);
#pragma unroll
      for (int q = 0; q < 4; ++q)
        *(float4*)(s + base16 + q * 4) =
            make_float4(u[q * 4], u[q * 4 + 1], u[q * 4 + 2], u[q * 4 + 3]);
    }
    __syncthreads();
    {  // bits 4..7 + epilogue
      float scale = 1.0f / sqrtf(S * 3072.0f);
      int b0 = (t & 15) + 256 * (t >> 4);
      float u[16];
#pragma unroll
      for (int j = 0; j < 16; ++j) {
        int i = b0 + 16 * j;
        u[j] = s[i + 4 * (i >> 5)];
      }
      reg_fwht<16, 1>(u);
#pragma unroll
      for (int j = 0; j < 16; ++j) {
        int i = b0 + 16 * j;
        if (i < 3072) b1w[i] = ib1[i] + u[j] * scale;
      }
    }
  } else {
    // ---- bias2: LL=1024, K=1024, DD=768 (generic path, tiny) ----
    float* tab2 = s;
    float* m42 = s + 1024;
    for (int i = t; i < 1024; i += 256) tab2[i] = BBb2[i] * theta[i];
    lds_fwht(tab2, 1024, t, 256);
    float lsum = 0.f;
    for (int i = t; i < 1024; i += 256) {
      float g = GGb2[i];
      lsum += g * g;
      m42[i] = tab2[Pib2[i] & 1023] * g;
    }
    for (int off = 32; off; off >>= 1) lsum += __shfl_down(lsum, off, 64);
    if ((t & 63) == 0) s[2048 + (t >> 6)] = lsum;
    lds_fwht(m42, 1024, t, 256);  // leading barrier covers s[2048..]
    float S = s[2048] + s[2049] + s[2050] + s[2051];
    float scale = 1.0f / sqrtf(S * 768.0f);
    for (int i = t; i < 768; i += 256) b2w[i] = ib2[i] + m42[i] * scale;
  }
}

// ---------------- k_f2c: FWHT over bits 13..21 + epilogue, both pipes -------
__global__ __launch_bounds__(256) void k_f2c(
    const unsigned short* __restrict__ m4b, const float* __restrict__ iW1,
    const float* __restrict__ iW2, const float* __restrict__ partial,
    __hip_bfloat16* __restrict__ W1b, __hip_bfloat16* __restrict__ W2b) {
  __shared__ __align__(16) float s[10480];
  __shared__ float red[4];
  int b = blockIdx.x, t = threadIdx.x;
  int pipe = b >> 9;
  int l0 = (b & 511) * 16;
  const unsigned short* mp = m4b + (long)pipe * LLW;
  const float* initW = pipe ? iW2 : iW1;
  unsigned short* outW = (unsigned short*)(pipe ? W2b : W1b);

  // reduce the 512 per-block sum(GG^2) partials (L2-hot) -> red[]
  {
    float ps = partial[pipe * 512 + t] + partial[pipe * 512 + 256 + t];
    for (int off = 32; off; off >>= 1) ps += __shfl_down(ps, off, 64);
    if ((t & 63) == 0) red[t >> 6] = ps;
  }

#pragma unroll
  for (int u = 0; u < 4; ++u) {  // 1024 half-rows of 8 bf16
    int idx = t + u * 256;
    int r = idx >> 1, h8 = (idx & 1) * 8;
    u16x8 raw = *(const u16x8*)(mp + (long)r * 8192 + l0 + h8);
    float* dp = s + r * 20 + (r >> 5) * 16 + h8;
    float4 f0, f1v;
    f0.x = __uint_as_float((unsigned)raw[0] << 16);
    f0.y = __uint_as_float((unsigned)raw[1] << 16);
    f0.z = __uint_as_float((unsigned)raw[2] << 16);
    f0.w = __uint_as_float((unsigned)raw[3] << 16);
    f1v.x = __uint_as_float((unsigned)raw[4] << 16);
    f1v.y = __uint_as_float((unsigned)raw[5] << 16);
    f1v.z = __uint_as_float((unsigned)raw[6] << 16);
    f1v.w = __uint_as_float((unsigned)raw[7] << 16);
    *(float4*)dp = f0;
    *(float4*)(dp + 4) = f1v;
  }
  __syncthreads();

  {  // row bits 0..4
    int c = t & 15, rg = t >> 4;
    float w[32];
#pragma unroll
    for (int j = 0; j < 32; ++j) {
      int r = rg * 32 + j;
      w[j] = s[r * 20 + (r >> 5) * 16 + c];
    }
    reg_fwht<32, 1>(w);
#pragma unroll
    for (int j = 0; j < 32; ++j) {
      int r = rg * 32 + j;
      s[r * 20 + (r >> 5) * 16 + c] = w[j];
    }
  }
  __syncthreads();

  {  // row bits 5..8
    int c = t & 15;
    float w[32];
#pragma unroll
    for (int k = 0; k < 2; ++k) {
      int b0 = (t >> 4) * 2 + k;
#pragma unroll
      for (int j4 = 0; j4 < 16; ++j4) {
        int r = b0 + 32 * j4;
        w[k * 16 + j4] = s[r * 20 + (r >> 5) * 16 + c];
      }
      reg_fwht<16, 1>(w + k * 16);
#pragma unroll
      for (int j4 = 0; j4 < 16; ++j4) {
        int r = b0 + 32 * j4;
        s[r * 20 + (r >> 5) * 16 + c] = w[k * 16 + j4];
      }
    }
  }
  __syncthreads();

  float S = red[0] + red[1] + red[2] + red[3];
  float scale = 1.0f / sqrtf(S * 2359296.0f);
#pragma unroll
  for (int u = 0; u < 5; ++u) {  // 288 rows * 4 f4-chunks = 1152
    int idx = t + u * 256;
    if (idx < 1152) {
      int r = idx >> 2, c4 = (idx & 3) * 4;
      const float* sp = s + r * 20 + (r >> 5) * 16 + c4;
      long gi = (long)r * 8192 + l0 + c4;
      float4 iv = *(const float4*)(initW + gi);
      ushort4 pk;
      pk.x = f2bf(iv.x + sp[0] * scale);
      pk.y = f2bf(iv.y + sp[1] * scale);
      pk.z = f2bf(iv.z + sp[2] * scale);
      pk.w = f2bf(iv.w + sp[3] * scale);
      *(ushort4*)(outW + gi) = pk;
    }
  }
}

// ---------------- MFMA GEMM, KCH interleaved K-chains -----------------------
template <int NACC, int KCH, bool RELU, bool OUT_BF16>
__global__ __launch_bounds__(256) void k_gemm(
    const __hip_bfloat16* __restrict__ A, const __hip_bfloat16* __restrict__ B,
    const float* __restrict__ bias, void* __restrict__ C, int M, int N, int K) {
  int wid = blockIdx.x * 4 + (threadIdx.x >> 6);
  int lane = threadIdx.x & 63;
  int ntiles = N / (16 * NACC);
  int mt = wid / ntiles, nt = wid % ntiles;
  if (mt * 16 >= M) return;
  int ml = lane & 15;
  int q = lane >> 4;
  const short* As = (const short*)A;
  const short* Bs = (const short*)B;
  long arow = (long)(mt * 16 + ml) * K + q * 8;
  int KH = K / KCH;
  f32x4 acc[KCH][NACC] = {};
  for (int k = 0; k < KH; k += 32) {
#pragma unroll
    for (int c = 0; c < KCH; ++c) {
      bf16x8 av = *(const bf16x8*)(As + arow + k + c * KH);
#pragma unroll
      for (int a = 0; a < NACC; ++a) {
        int n = nt * 16 * NACC + a * 16 + ml;
        bf16x8 bv = *(const bf16x8*)(Bs + (long)n * K + q * 8 + k + c * KH);
        acc[c][a] =
            __builtin_amdgcn_mfma_f32_16x16x32_bf16(av, bv, acc[c][a], 0, 0, 0);
      }
    }
  }
#pragma unroll
  for (int a = 0; a < NACC; ++a) {
    int n = nt * 16 * NACC + a * 16 + ml;
    float bv = bias[n];
#pragma unroll
    for (int r = 0; r < 4; ++r) {
      float vv = bv;
#pragma unroll
      for (int c = 0; c < KCH; ++c) vv += acc[c][a][r];
      int mm = mt * 16 + q * 4 + r;
      if (RELU) vv = fmaxf(vv, 0.f);
      if (OUT_BF16)
        ((__hip_bfloat16*)C)[(long)mm * N + n] = __float2bfloat16(vv);
      else
        ((float*)C)[(long)mm * N + n] = vv;
    }
  }
}

// ---------------- workspace layout (bytes) ----------------------------------
#define OFF_PART 0                          // 1024 f32 partials
#define OFF_M2S 4096
#define OFF_M4B (OFF_M2S + 16384)           // 2*LLW bf16 = 16 MiB
#define OFF_W1B (OFF_M4B + 2 * LLW * 2)     // 2359296 bf16
#define OFF_W2B (OFF_W1B + 4718592)
#define OFF_HB (OFF_W2B + 4718592)          // 256*3072 bf16
#define OFF_XB (OFF_HB + 1572864)           // 256*768 bf16
#define OFF_B1 (OFF_XB + 393216)            // 3072 f32
#define OFF_B2 (OFF_B1 + 12288)             // 768 f32

extern "C" void kernel_launch(void* const* d_in, const int* in_sizes, int n_in,
                              void* d_out, int out_size, void* d_ws,
                              size_t ws_size, hipStream_t stream) {
  const float* x = (const float*)d_in[0];
  const float* theta = (const float*)d_in[1];
  const float* iW1 = (const float*)d_in[2];
  const float* ib1 = (const float*)d_in[3];
  const float* iW2 = (const float*)d_in[4];
  const float* ib2 = (const float*)d_in[5];
  const float* BB_W1 = (const float*)d_in[6];
  const int* Pi_W1 = (const int*)d_in[7];
  const float* GG_W1 = (const float*)d_in[8];
  const float* BB_b1 = (const float*)d_in[9];
  const int* Pi_b1 = (const int*)d_in[10];
  const float* GG_b1 = (const float*)d_in[11];
  const float* BB_W2 = (const float*)d_in[12];
  const int* Pi_W2 = (const int*)d_in[13];
  const float* GG_W2 = (const float*)d_in[14];
  const float* BB_b2 = (const float*)d_in[15];
  const int* Pi_b2 = (const int*)d_in[16];
  const float* GG_b2 = (const float*)d_in[17];

  char* ws = (char*)d_ws;
  float* partial = (float*)(ws + OFF_PART);
  float* m2s = (float*)(ws + OFF_M2S);
  unsigned short* m4b = (unsigned short*)(ws + OFF_M4B);
  __hip_bfloat16* W1b = (__hip_bfloat16*)(ws + OFF_W1B);
  __hip_bfloat16* W2b = (__hip_bfloat16*)(ws + OFF_W2B);
  __hip_bfloat16* hb = (__hip_bfloat16*)(ws + OFF_HB);
  __hip_bfloat16* xb = (__hip_bfloat16*)(ws + OFF_XB);
  float* b1w = (float*)(ws + OFF_B1);
  float* b2w = (float*)(ws + OFF_B2);

  k_pre<<<98, 256, 0, stream>>>(theta, BB_W1, BB_W2, m2s, x, xb);
  k_front<<<1026, 256, 0, stream>>>(Pi_W1, GG_W1, Pi_W2, GG_W2, m2s, m4b,
                                    partial, theta, BB_b1, Pi_b1, GG_b1, ib1,
                                    b1w, BB_b2, Pi_b2, GG_b2, ib2, b2w);
  k_f2c<<<1024, 256, 0, stream>>>(m4b, iW1, iW2, partial, W1b, W2b);
  k_gemm<2, 1, true, true><<<384, 256, 0, stream>>>(xb, W1b, b1w, hb, 256,
                                                    3072, 768);
  k_gemm<1, 2, false, false><<<192, 256, 0, stream>>>(hb, W2b, b2w, d_out, 256,
                                                      768, 3072);
}

// Round 6
// 216.719 us; speedup vs baseline: 1.8303x; 1.0471x over previous
//
#include <hip/hip_runtime.h>
#include <hip/hip_bf16.h>

typedef __attribute__((ext_vector_type(8))) short bf16x8;
typedef __attribute__((ext_vector_type(8))) unsigned short u16x8;
typedef __attribute__((ext_vector_type(4))) float f32x4;

// ---------------- in-register FWHT over N entries spaced S apart ------------
template <int N, int S>
__device__ __forceinline__ void reg_fwht(float* v) {
#pragma unroll
  for (int h = 1; h < N; h <<= 1)
#pragma unroll
    for (int g = 0; g < N; g += 2 * h)
#pragma unroll
      for (int j = 0; j < h; ++j) {
        float a = v[(g + j) * S], b = v[(g + j + h) * S];
        v[(g + j) * S] = a + b;
        v[(g + j + h) * S] = a - b;
      }
}

__device__ __forceinline__ unsigned short f2bf(float f) {
  unsigned u = __float_as_uint(f);
  unsigned r = (u + 0x7fff + ((u >> 16) & 1)) >> 16;
  return (unsigned short)r;
}

// generic barriered LDS FWHT (tiny bias2 only)
__device__ __forceinline__ void lds_fwht(float* s, int n, int tid, int T) {
  for (int h = 1; h < n; h <<= 1) {
    __syncthreads();
    for (int t = tid; t < (n >> 1); t += T) {
      int i0 = ((t & ~(h - 1)) << 1) | (t & (h - 1));
      int i1 = i0 + h;
      float a = s[i0], b = s[i1];
      s[i0] = a + b;
      s[i1] = a - b;
    }
  }
  __syncthreads();
}

// ---------------- register FWHT-2048 with 256 threads -----------------------
__device__ __forceinline__ void fwht2048_block(float w[8], float* pad,
                                               float* dst, int t) {
  reg_fwht<8, 1>(w);  // bits 8..10
#pragma unroll
  for (int j = 0; j < 8; ++j) {
    int i = t + 256 * j;
    pad[i + 4 * (i >> 5)] = w[j];
  }
  __syncthreads();
  {  // bits 0..2
    int base = 8 * t + 4 * (t >> 2);
    float4 a = *(float4*)(pad + base);
    float4 b = *(float4*)(pad + base + 4);
    float u[8] = {a.x, a.y, a.z, a.w, b.x, b.y, b.z, b.w};
    reg_fwht<8, 1>(u);
    *(float4*)(pad + base) = make_float4(u[0], u[1], u[2], u[3]);
    *(float4*)(pad + base + 4) = make_float4(u[4], u[5], u[6], u[7]);
  }
  __syncthreads();
  {  // bits 3..5
    int b0 = (t & 7) + 64 * (t >> 3);
    float u[8];
#pragma unroll
    for (int j = 0; j < 8; ++j) {
      int i = b0 + 8 * j;
      u[j] = pad[i + 4 * (i >> 5)];
    }
    reg_fwht<8, 1>(u);
#pragma unroll
    for (int j = 0; j < 8; ++j) {
      int i = b0 + 8 * j;
      pad[i + 4 * (i >> 5)] = u[j];
    }
  }
  __syncthreads();
  // bits 6..7 -> dst unpadded
#pragma unroll
  for (int g = 0; g < 2; ++g) {
    int b0 = (t & 63) + 256 * ((g << 2) | (t >> 6));
    float u[4];
#pragma unroll
    for (int j = 0; j < 4; ++j) {
      int i = b0 + 64 * j;
      u[j] = pad[i + 4 * (i >> 5)];
    }
    reg_fwht<4, 1>(u);
#pragma unroll
    for (int j = 0; j < 4; ++j) dst[b0 + 64 * j] = u[j];
  }
  __syncthreads();
}

// ---------------- k_pre: m2 tables (blocks 0,1) + x->bf16 (blocks 2..97) ----
__global__ __launch_bounds__(256) void k_pre(
    const float* __restrict__ theta, const float* __restrict__ BB0,
    const float* __restrict__ BB1, float* __restrict__ m2s,
    const float* __restrict__ x, __hip_bfloat16* __restrict__ xb) {
  __shared__ __align__(16) float pad[2304];
  int b = blockIdx.x, t = threadIdx.x;
  if (b < 2) {
    const float* BB = b ? BB1 : BB0;
    float w[8];
#pragma unroll
    for (int j = 0; j < 8; ++j) {
      int i = t + 256 * j;
      w[j] = BB[i] * theta[i];
    }
    fwht2048_block(w, pad, m2s + b * 2048, t);
  } else {
    int id0 = (b - 2) * 256 + t;
#pragma unroll
    for (int it = 0; it < 2; ++it) {
      int id = id0 + it * 24576;
      float4 xv = ((const float4*)x)[id];
      ushort4 o;
      o.x = f2bf(xv.x);
      o.y = f2bf(xv.y);
      o.z = f2bf(xv.z);
      o.w = f2bf(xv.w);
      ((ushort4*)xb)[id] = o;
    }
  }
}

#define LLW 4194304

// ---------------- k_front: biases (blocks 0,1) + f1 x2 pipes (2..1025) ------
// m4b written TRANSPOSED by 16-col groups: elem (chunk r, pos c) stored at
// (c>>4)*8192 + r*16 + (c&15)  -> k_f2c reads 16KB contiguous per block.
__global__ __launch_bounds__(256) void k_front(
    const int* __restrict__ Pi1, const float* __restrict__ GG1,
    const int* __restrict__ Pi2, const float* __restrict__ GG2,
    const float* __restrict__ m2s, unsigned short* __restrict__ m4b,
    float* __restrict__ partial, const float* __restrict__ theta,
    const float* __restrict__ BBb1, const int* __restrict__ Pib1,
    const float* __restrict__ GGb1, const float* __restrict__ ib1,
    float* __restrict__ b1w, const float* __restrict__ BBb2,
    const int* __restrict__ Pib2, const float* __restrict__ GGb2,
    const float* __restrict__ ib2, float* __restrict__ b2w) {
  __shared__ __align__(16) float s[9216];  // tab aliases s[0:2048]
  __shared__ float red[4];
  int b = blockIdx.x, t = threadIdx.x;

  if (b >= 2) {
    int bb = b - 2;
    int pipe = bb >> 9, chunk = bb & 511;
    const int* Pi = pipe ? Pi2 : Pi1;
    const float* GG = pipe ? GG2 : GG1;
    const float* mm = m2s + pipe * 2048;
    for (int u = t; u < 512; u += 256) ((float4*)s)[u] = ((const float4*)mm)[u];
    __syncthreads();

    long base = (long)chunk * 8192;
    const int4* p4 = (const int4*)(Pi + base);
    const float4* g4 = (const float4*)(GG + base);
    float v[32];
    float lsum = 0.f;
#pragma unroll
    for (int j = 0; j < 8; ++j) {  // i = t*4 + e + j*1024
      int4 p = p4[t + j * 256];
      float4 g = g4[t + j * 256];
      lsum += g.x * g.x + g.y * g.y + g.z * g.z + g.w * g.w;
      v[j * 4 + 0] = s[p.x & 2047] * g.x;
      v[j * 4 + 1] = s[p.y & 2047] * g.y;
      v[j * 4 + 2] = s[p.z & 2047] * g.z;
      v[j * 4 + 3] = s[p.w & 2047] * g.w;
    }
    for (int off = 32; off; off >>= 1) lsum += __shfl_down(lsum, off, 64);
    if ((t & 63) == 0) red[t >> 6] = lsum;

#pragma unroll
    for (int e = 0; e < 4; ++e) reg_fwht<8, 4>(v + e);  // bits 10..12

    __syncthreads();  // tab reads + red writes complete; s reusable
    if (t == 0) partial[pipe * 512 + chunk] = red[0] + red[1] + red[2] + red[3];

#pragma unroll
    for (int j = 0; j < 8; ++j) {
      int A = t * 4 + 4 * (t >> 3) + j * 1152;
      *(float4*)(s + A) =
          make_float4(v[j * 4], v[j * 4 + 1], v[j * 4 + 2], v[j * 4 + 3]);
    }
    __syncthreads();
    {  // bits 5..9
      int b0 = (t & 31) + (t >> 5) * 1024;
      float w[32];
#pragma unroll
      for (int j2 = 0; j2 < 32; ++j2) {
        int i = b0 + j2 * 32;
        w[j2] = s[i + 4 * (i >> 5)];
      }
      reg_fwht<32, 1>(w);
#pragma unroll
      for (int j2 = 0; j2 < 32; ++j2) {
        int i = b0 + j2 * 32;
        s[i + 4 * (i >> 5)] = w[j2];
      }
    }
    __syncthreads();
    // bits 0..4: thread owns c = t*32..t*32+31 (contiguous)
#pragma unroll
    for (int q = 0; q < 8; ++q) {
      float4 r = *(const float4*)(s + t * 36 + q * 4);
      v[q * 4 + 0] = r.x;
      v[q * 4 + 1] = r.y;
      v[q * 4 + 2] = r.z;
      v[q * 4 + 3] = r.w;
    }
    reg_fwht<32, 1>(v);
    // transposed write: col-groups 2t, 2t+1; 32B per group
    unsigned short* o = m4b + (long)pipe * LLW;
    long a0 = (long)(2 * t) * 8192 + (long)chunk * 16;
#pragma unroll
    for (int q = 0; q < 4; ++q) {
      u16x8 pk;
#pragma unroll
      for (int e = 0; e < 8; ++e) pk[e] = f2bf(v[q * 8 + e]);
      *(u16x8*)(o + a0 + (q >> 1) * 8192 + (q & 1) * 8) = pk;
    }
  } else if (b == 0) {
    // ---- bias1: LL=4096, K=2048, DD=3072 ----
    float* tabd = s + 6144;
    float w[8];
#pragma unroll
    for (int j = 0; j < 8; ++j) {
      int i = t + 256 * j;
      w[j] = BBb1[i] * theta[i];
    }
    fwht2048_block(w, s, tabd, t);

    float w16[16];
    float lsum = 0.f;
#pragma unroll
    for (int j = 0; j < 16; ++j) {
      int i = t + 256 * j;
      float g = GGb1[i];
      lsum += g * g;
      w16[j] = tabd[Pib1[i] & 2047] * g;
    }
    reg_fwht<16, 1>(w16);  // bits 8..11
#pragma unroll
    for (int j = 0; j < 16; ++j) {
      int i = t + 256 * j;
      s[i + 4 * (i >> 5)] = w16[j];
    }
    for (int off = 32; off; off >>= 1) lsum += __shfl_down(lsum, off, 64);
    if ((t & 63) == 0) s[4608 + (t >> 6)] = lsum;
    __syncthreads();
    float S = s[4608] + s[4609] + s[4610] + s[4611];
    {  // bits 0..3
      int base16 = 16 * t + 4 * (t >> 1);
      float u[16];
#pragma unroll
      for (int q = 0; q < 4; ++q) {
        float4 r = *(float4*)(s + base16 + q * 4);
        u[q * 4 + 0] = r.x;
        u[q * 4 + 1] = r.y;
        u[q * 4 + 2] = r.z;
        u[q * 4 + 3] = r.w;
      }
      reg_fwht<16, 1>(u);
#pragma unroll
      for (int q = 0; q < 4; ++q)
        *(float4*)(s + base16 + q * 4) =
            make_float4(u[q * 4], u[q * 4 + 1], u[q * 4 + 2], u[q * 4 + 3]);
    }
    __syncthreads();
    {  // bits 4..7 + epilogue
      float scale = 1.0f / sqrtf(S * 3072.0f);
      int b0 = (t & 15) + 256 * (t >> 4);
      float u[16];
#pragma unroll
      for (int j = 0; j < 16; ++j) {
        int i = b0 + 16 * j;
        u[j] = s[i + 4 * (i >> 5)];
      }
      reg_fwht<16, 1>(u);
#pragma unroll
      for (int j = 0; j < 16; ++j) {
        int i = b0 + 16 * j;
        if (i < 3072) b1w[i] = ib1[i] + u[j] * scale;
      }
    }
  } else {
    // ---- bias2: LL=1024, K=1024, DD=768 ----
    float* tab2 = s;
    float* m42 = s + 1024;
    for (int i = t; i < 1024; i += 256) tab2[i] = BBb2[i] * theta[i];
    lds_fwht(tab2, 1024, t, 256);
    float lsum = 0.f;
    for (int i = t; i < 1024; i += 256) {
      float g = GGb2[i];
      lsum += g * g;
      m42[i] = tab2[Pib2[i] & 1023] * g;
    }
    for (int off = 32; off; off >>= 1) lsum += __shfl_down(lsum, off, 64);
    if ((t & 63) == 0) s[2048 + (t >> 6)] = lsum;
    lds_fwht(m42, 1024, t, 256);
    float S = s[2048] + s[2049] + s[2050] + s[2051];
    float scale = 1.0f / sqrtf(S * 768.0f);
    for (int i = t; i < 768; i += 256) b2w[i] = ib2[i] + m42[i] * scale;
  }
}

// ---------------- k_f2c: FWHT over bits 13..21 + epilogue, both pipes -------
// col-group swizzle g: pairs (2m,2m+1) share an initW cache line and land on
// the same XCD (blockIdx%8) for L2 reuse.
__global__ __launch_bounds__(256) void k_f2c(
    const unsigned short* __restrict__ m4b, const float* __restrict__ iW1,
    const float* __restrict__ iW2, const float* __restrict__ partial,
    __hip_bfloat16* __restrict__ W1b, __hip_bfloat16* __restrict__ W2b) {
  __shared__ __align__(16) float s[10480];
  __shared__ float red[4];
  int b = blockIdx.x, t = threadIdx.x;
  int pipe = b >> 9;
  int lb = b & 511;
  int g = ((lb & 7) << 6) | (lb >> 3);
  int l0 = g * 16;
  const unsigned short* mp = m4b + (long)pipe * LLW + (long)g * 8192;
  const float* initW = pipe ? iW2 : iW1;
  unsigned short* outW = (unsigned short*)(pipe ? W2b : W1b);

  // reduce the 512 per-block sum(GG^2) partials (L2-hot) -> red[]
  {
    float ps = partial[pipe * 512 + t] + partial[pipe * 512 + 256 + t];
    for (int off = 32; off; off >>= 1) ps += __shfl_down(ps, off, 64);
    if ((t & 63) == 0) red[t >> 6] = ps;
  }

  // contiguous 16KB read: elem idx = r*16 + cl
#pragma unroll
  for (int q = 0; q < 4; ++q) {
    u16x8 raw = *(const u16x8*)(mp + t * 32 + q * 8);
    int r = 2 * t + (q >> 1), cb = (q & 1) * 8;
    float* dp = s + r * 20 + (r >> 5) * 16 + cb;
    float4 f0, f1v;
    f0.x = __uint_as_float((unsigned)raw[0] << 16);
    f0.y = __uint_as_float((unsigned)raw[1] << 16);
    f0.z = __uint_as_float((unsigned)raw[2] << 16);
    f0.w = __uint_as_float((unsigned)raw[3] << 16);
    f1v.x = __uint_as_float((unsigned)raw[4] << 16);
    f1v.y = __uint_as_float((unsigned)raw[5] << 16);
    f1v.z = __uint_as_float((unsigned)raw[6] << 16);
    f1v.w = __uint_as_float((unsigned)raw[7] << 16);
    *(float4*)dp = f0;
    *(float4*)(dp + 4) = f1v;
  }
  __syncthreads();

  {  // row bits 0..4
    int c = t & 15, rg = t >> 4;
    float w[32];
#pragma unroll
    for (int j = 0; j < 32; ++j) {
      int r = rg * 32 + j;
      w[j] = s[r * 20 + (r >> 5) * 16 + c];
    }
    reg_fwht<32, 1>(w);
#pragma unroll
    for (int j = 0; j < 32; ++j) {
      int r = rg * 32 + j;
      s[r * 20 + (r >> 5) * 16 + c] = w[j];
    }
  }
  __syncthreads();

  {  // row bits 5..8
    int c = t & 15;
    float w[32];
#pragma unroll
    for (int k = 0; k < 2; ++k) {
      int b0 = (t >> 4) * 2 + k;
#pragma unroll
      for (int j4 = 0; j4 < 16; ++j4) {
        int r = b0 + 32 * j4;
        w[k * 16 + j4] = s[r * 20 + (r >> 5) * 16 + c];
      }
      reg_fwht<16, 1>(w + k * 16);
#pragma unroll
      for (int j4 = 0; j4 < 16; ++j4) {
        int r = b0 + 32 * j4;
        s[r * 20 + (r >> 5) * 16 + c] = w[k * 16 + j4];
      }
    }
  }
  __syncthreads();

  float S = red[0] + red[1] + red[2] + red[3];
  float scale = 1.0f / sqrtf(S * 2359296.0f);
#pragma unroll
  for (int u = 0; u < 5; ++u) {  // 288 rows * 4 f4-chunks = 1152
    int idx = t + u * 256;
    if (idx < 1152) {
      int r = idx >> 2, c4 = (idx & 3) * 4;
      const float* sp = s + r * 20 + (r >> 5) * 16 + c4;
      long gi = (long)r * 8192 + l0 + c4;
      float4 iv = *(const float4*)(initW + gi);
      ushort4 pk;
      pk.x = f2bf(iv.x + sp[0] * scale);
      pk.y = f2bf(iv.y + sp[1] * scale);
      pk.z = f2bf(iv.z + sp[2] * scale);
      pk.w = f2bf(iv.w + sp[3] * scale);
      *(ushort4*)(outW + gi) = pk;
    }
  }
}

// ---------------- MFMA GEMM, in-block split-K + LDS reduce ------------------
// grid must be exactly (M/16)*(N/16/NACC)*SPLITK/4 blocks of 256 threads.
template <int NACC, int SPLITK, bool RELU, bool OUT_BF16>
__global__ __launch_bounds__(256) void k_gemm(
    const __hip_bfloat16* __restrict__ A, const __hip_bfloat16* __restrict__ B,
    const float* __restrict__ bias, void* __restrict__ C, int M, int N, int K) {
  __shared__ float red[4 * NACC * 320];  // [wave][acc][lane*5+r], pad 5
  int wave = threadIdx.x >> 6, lane = threadIdx.x & 63;
  int tileid = blockIdx.x * (4 / SPLITK) + wave / SPLITK;
  int sk = wave % SPLITK;
  int ntiles = N / (16 * NACC);
  int mt = tileid / ntiles, nt = tileid % ntiles;
  int ml = lane & 15;
  int q = lane >> 4;
  const short* As = (const short*)A;
  const short* Bs = (const short*)B;
  long arow = (long)(mt * 16 + ml) * K + q * 8;
  int KS = K / SPLITK, k0 = sk * KS;
  f32x4 acc[NACC] = {};
  for (int k = k0; k < k0 + KS; k += 32) {
    bf16x8 av = *(const bf16x8*)(As + arow + k);
#pragma unroll
    for (int a = 0; a < NACC; ++a) {
      int n = nt * 16 * NACC + a * 16 + ml;
      bf16x8 bv = *(const bf16x8*)(Bs + (long)n * K + q * 8 + k);
      acc[a] = __builtin_amdgcn_mfma_f32_16x16x32_bf16(av, bv, acc[a], 0, 0, 0);
    }
  }
#pragma unroll
  for (int a = 0; a < NACC; ++a)
#pragma unroll
    for (int r = 0; r < 4; ++r)
      red[(wave * NACC + a) * 320 + lane * 5 + r] = acc[a][r];
  __syncthreads();
  if (sk == 0) {
#pragma unroll
    for (int a = 0; a < NACC; ++a) {
      int n = nt * 16 * NACC + a * 16 + ml;
      float bv = bias[n];
#pragma unroll
      for (int r = 0; r < 4; ++r) {
        float vv = bv;
#pragma unroll
        for (int j = 0; j < SPLITK; ++j)
          vv += red[((wave + j) * NACC + a) * 320 + lane * 5 + r];
        int mm = mt * 16 + q * 4 + r;
        if (RELU) vv = fmaxf(vv, 0.f);
        if (OUT_BF16)
          ((__hip_bfloat16*)C)[(long)mm * N + n] = __float2bfloat16(vv);
        else
          ((float*)C)[(long)mm * N + n] = vv;
      }
    }
  }
}

// ---------------- workspace layout (bytes) ----------------------------------
#define OFF_PART 0                          // 1024 f32 partials
#define OFF_M2S 4096
#define OFF_M4B (OFF_M2S + 16384)           // 2*LLW bf16 = 16 MiB
#define OFF_W1B (OFF_M4B + 2 * LLW * 2)     // 2359296 bf16
#define OFF_W2B (OFF_W1B + 4718592)
#define OFF_HB (OFF_W2B + 4718592)          // 256*3072 bf16
#define OFF_XB (OFF_HB + 1572864)           // 256*768 bf16
#define OFF_B1 (OFF_XB + 393216)            // 3072 f32
#define OFF_B2 (OFF_B1 + 12288)             // 768 f32

extern "C" void kernel_launch(void* const* d_in, const int* in_sizes, int n_in,
                              void* d_out, int out_size, void* d_ws,
                              size_t ws_size, hipStream_t stream) {
  const float* x = (const float*)d_in[0];
  const float* theta = (const float*)d_in[1];
  const float* iW1 = (const float*)d_in[2];
  const float* ib1 = (const float*)d_in[3];
  const float* iW2 = (const float*)d_in[4];
  const float* ib2 = (const float*)d_in[5];
  const float* BB_W1 = (const float*)d_in[6];
  const int* Pi_W1 = (const int*)d_in[7];
  const float* GG_W1 = (const float*)d_in[8];
  const float* BB_b1 = (const float*)d_in[9];
  const int* Pi_b1 = (const int*)d_in[10];
  const float* GG_b1 = (const float*)d_in[11];
  const float* BB_W2 = (const float*)d_in[12];
  const int* Pi_W2 = (const int*)d_in[13];
  const float* GG_W2 = (const float*)d_in[14];
  const float* BB_b2 = (const float*)d_in[15];
  const int* Pi_b2 = (const int*)d_in[16];
  const float* GG_b2 = (const float*)d_in[17];

  char* ws = (char*)d_ws;
  float* partial = (float*)(ws + OFF_PART);
  float* m2s = (float*)(ws + OFF_M2S);
  unsigned short* m4b = (unsigned short*)(ws + OFF_M4B);
  __hip_bfloat16* W1b = (__hip_bfloat16*)(ws + OFF_W1B);
  __hip_bfloat16* W2b = (__hip_bfloat16*)(ws + OFF_W2B);
  __hip_bfloat16* hb = (__hip_bfloat16*)(ws + OFF_HB);
  __hip_bfloat16* xb = (__hip_bfloat16*)(ws + OFF_XB);
  float* b1w = (float*)(ws + OFF_B1);
  float* b2w = (float*)(ws + OFF_B2);

  k_pre<<<98, 256, 0, stream>>>(theta, BB_W1, BB_W2, m2s, x, xb);
  k_front<<<1026, 256, 0, stream>>>(Pi_W1, GG_W1, Pi_W2, GG_W2, m2s, m4b,
                                    partial, theta, BB_b1, Pi_b1, GG_b1, ib1,
                                    b1w, BB_b2, Pi_b2, GG_b2, ib2, b2w);
  k_f2c<<<1024, 256, 0, stream>>>(m4b, iW1, iW2, partial, W1b, W2b);
  // h = relu(x @ W1^T + b1): 16*96 tiles, SPLITK=2 -> 768 blocks
  k_gemm<2, 2, true, true><<<768, 256, 0, stream>>>(xb, W1b, b1w, hb, 256,
                                                    3072, 768);
  // out = h @ W2^T + b2: 16*48 tiles, SPLITK=4 -> 768 blocks
  k_gemm<1, 4, false, false><<<768, 256, 0, stream>>>(hb, W2b, b2w, d_out, 256,
                                                      768, 3072);
}